// Round 9
// baseline (175.278 us; speedup 1.0000x reference)
//
#include <hip/hip_runtime.h>

// RNN scan: h_{t+1} = relu(W_hh @ h_t + x_t * w_x), out = W_hy @ h_T
// B=8192, T=512, H=64.
// Round 9: replace 4x mfma_f32_32x32x16_bf16 (4 serialized ~90cyc blocks)
// with ONE v_mfma_scale_f32_32x32x64_f8f6f4 per wave per step (M=32, K=64).
//   - W, h in OCP fp8 e4m3, both pre-scaled x256 (normal range), HW dequant
//     via E8M0 scales 119/119 (2^-8 each). x-term stays f32-exact as C-in.
//   - A layout (by analogy w/ verified bf16): row=lane&31, k=32*(lane>>5)+byte,
//     bytes sequential through 8 regs. B: col=lane&31, same k mapping.
//   - pack: pk_max(relu) -> *256 -> 8x cvt_pk_fp8 -> quads Q_i (C-regs 4i..4i+3
//     = rows 8i+4*sel+0..3 => B-reg 2i+sel). 4 copies + 4 permlane32_swap give
//     every lane the full own-half 32 bytes (B-regs: Q'0,P'0,Q'1,P'1,...).
//   - exchange: r8's zero-conflict [buf][slot][word][lane] LDS pattern;
//     read addr is lane-universal: slot = lane>>5 (own slot reads own data).
//   - x-term hoisted one step ahead.
// Layouts verified rounds 1-8: C: col=lane&31, row=(reg&3)+8*(reg>>2)+4*(lane>>5)
//   permlane32_swap(X,Y): X'={self X|partner Y}, Y'={partner X|self Y}

typedef float f32x16 __attribute__((ext_vector_type(16)));
typedef int i32x8 __attribute__((ext_vector_type(8)));
typedef unsigned int u32x4 __attribute__((ext_vector_type(4)));

#define RNN_B 8192
#define RNN_T 512
#define RNN_H 64
#define E8M0_2POWM8 119   // 127 - 8

__global__ __launch_bounds__(128, 1) void rnn_scan_kernel(
    const float* __restrict__ x,
    const float* __restrict__ Wxh,
    const float* __restrict__ Whh,
    const float* __restrict__ Why,
    float* __restrict__ out)
{
  const int tid  = threadIdx.x;
  const int wv   = tid >> 6;      // owns C rows == k-range [32wv, 32wv+32)
  const int lane = tid & 63;
  const int col  = lane & 31;
  const int sel  = lane >> 5;
  const int b0   = blockIdx.x * 32;

  // [buf][slot][word][lane]; slot s holds h rows [32s, 32s+32) as B-bytes
  __shared__ u32x4 xch[2][2][2][64];          // 8 KiB
  __shared__ float partial[2][32];

  // ---- A fp8 frag: W[32wv+col][32*sel + 4r + b] * 256 -> e4m3 ----
  i32x8 Af;
  {
    const float* wp = Whh + (size_t)(32 * wv + col) * RNN_H + 32 * sel;
#pragma unroll
    for (int r = 0; r < 8; ++r) {
      float4 w = *(const float4*)(wp + 4 * r);
      int v = __builtin_amdgcn_cvt_pk_fp8_f32(w.x * 256.0f, w.y * 256.0f, 0, false);
      v     = __builtin_amdgcn_cvt_pk_fp8_f32(w.z * 256.0f, w.w * 256.0f, v, true);
      Af[r] = v;
    }
  }

  // ---- w_x per accumulator slot (this wave's rows) ----
  f32x16 wxv;
#pragma unroll
  for (int r = 0; r < 16; ++r)
    wxv[r] = Wxh[32 * wv + (r & 3) + 8 * (r >> 2) + 4 * sel];

  const float* xrow = x + (size_t)(b0 + col) * RNN_T;
  float4 xc0 = *(const float4*)(xrow);
  float4 xc1 = *(const float4*)(xrow + 4);

  f32x16 zf = {};
  f32x16 acc = {};                 // own rows' pre-relu h
  i32x8 Bv = {};                   // fp8 B operand (h_0 = 0 -> bytes 0)
  f32x16 xterm = wxv * xc0.x;      // step-0 x-term (f32-exact), kept 1 ahead

  for (int tb = 0; tb < RNN_T; tb += 8) {
    const int tn = (tb + 8 < RNN_T) ? tb + 8 : tb;
    float4 xn0 = *(const float4*)(xrow + tn);
    float4 xn1 = *(const float4*)(xrow + tn + 4);
    const float xs[8] = {xc0.x, xc0.y, xc0.z, xc0.w, xc1.x, xc1.y, xc1.z, xc1.w};
#pragma unroll
    for (int j = 0; j < 8; ++j) {
      // ONE matrix op: acc = dequant(W_fp8) @ dequant(h_fp8) + x*wx
      acc = __builtin_amdgcn_mfma_scale_f32_32x32x64_f8f6f4(
          Af, Bv, xterm, 0 /*cbsz=fp8*/, 0 /*blgp=fp8*/,
          0, E8M0_2POWM8, 0, E8M0_2POWM8);

      // x-term for NEXT step (independent of acc)
      const float xnxt = (j < 7) ? xs[j + 1] : xn0.x;
      xterm = wxv * xnxt;

      // pack own rows: relu -> *256 -> e4m3 quads
      f32x16 hr = __builtin_elementwise_max(acc, zf) * 256.0f;
      unsigned Q0 = (unsigned)__builtin_amdgcn_cvt_pk_fp8_f32(hr[0],  hr[1],  0, false);
      Q0 = (unsigned)__builtin_amdgcn_cvt_pk_fp8_f32(hr[2],  hr[3],  (int)Q0, true);
      unsigned Q1 = (unsigned)__builtin_amdgcn_cvt_pk_fp8_f32(hr[4],  hr[5],  0, false);
      Q1 = (unsigned)__builtin_amdgcn_cvt_pk_fp8_f32(hr[6],  hr[7],  (int)Q1, true);
      unsigned Q2 = (unsigned)__builtin_amdgcn_cvt_pk_fp8_f32(hr[8],  hr[9],  0, false);
      Q2 = (unsigned)__builtin_amdgcn_cvt_pk_fp8_f32(hr[10], hr[11], (int)Q2, true);
      unsigned Q3 = (unsigned)__builtin_amdgcn_cvt_pk_fp8_f32(hr[12], hr[13], 0, false);
      Q3 = (unsigned)__builtin_amdgcn_cvt_pk_fp8_f32(hr[14], hr[15], (int)Q3, true);

      // assemble full own-half bytes in every lane:
      // Q'_i = sigma0 quad (B-reg 2i), P'_i = sigma1 quad (B-reg 2i+1)
      unsigned P0 = Q0, P1 = Q1, P2 = Q2, P3 = Q3;
      asm("v_permlane32_swap_b32 %0, %1" : "+v"(Q0), "+v"(P0));
      asm("v_permlane32_swap_b32 %0, %1" : "+v"(Q1), "+v"(P1));
      asm("v_permlane32_swap_b32 %0, %1" : "+v"(Q2), "+v"(P2));
      asm("v_permlane32_swap_b32 %0, %1" : "+v"(Q3), "+v"(P3));

      // publish own k-half into buf q; fetch both halves (universal addr)
      const int q = (j & 1) ^ 1;
      u32x4 lo4 = {Q0, P0, Q1, P1};
      u32x4 hi4 = {Q2, P2, Q3, P3};
      xch[q][wv][0][lane] = lo4;
      xch[q][wv][1][lane] = hi4;
      asm volatile("s_waitcnt lgkmcnt(0)\n\ts_barrier" ::: "memory");
      u32x4 rlo = xch[q][sel][0][lane];   // slot = lane>>5: k = 32*sel + byte
      u32x4 rhi = xch[q][sel][1][lane];
      Bv[0] = rlo[0]; Bv[1] = rlo[1]; Bv[2] = rlo[2]; Bv[3] = rlo[3];
      Bv[4] = rhi[0]; Bv[5] = rhi[1]; Bv[6] = rhi[2]; Bv[7] = rhi[3];
    }
    xc0 = xn0; xc1 = xn1;
  }

  // ---- epilogue: out[b] = sum over own rows, then cross-wave ----
  float pw = 0.0f;
#pragma unroll
  for (int r = 0; r < 16; ++r) {
    const int row = 32 * wv + (r & 3) + 8 * (r >> 2) + 4 * sel;
    pw += Why[row] * fmaxf(acc[r], 0.0f);
  }
  pw += __shfl_xor(pw, 32, 64);
  if (lane < 32) partial[wv][col] = pw;
  __syncthreads();
  if (wv == 0 && lane < 32) out[b0 + col] = partial[0][col] + partial[1][col];
}

extern "C" void kernel_launch(void* const* d_in, const int* in_sizes, int n_in,
                              void* d_out, int out_size, void* d_ws, size_t ws_size,
                              hipStream_t stream) {
  const float* x   = (const float*)d_in[0];
  const float* Wxh = (const float*)d_in[1];
  const float* Whh = (const float*)d_in[2];
  const float* Why = (const float*)d_in[3];
  float* out = (float*)d_out;
  (void)in_sizes; (void)n_in; (void)out_size; (void)d_ws; (void)ws_size;
  rnn_scan_kernel<<<dim3(RNN_B / 32), dim3(128), 0, stream>>>(x, Wxh, Whh, Why, out);
}

// Round 10
// 89.808 us; speedup vs baseline: 1.9517x; 1.9517x over previous
//
#include <hip/hip_runtime.h>

// RNN scan: h_{t+1} = relu(W_hh @ h_t + x_t * w_x), out = W_hy @ h_T
// B=8192, T=512, H=64.
// Round 10: 16x16x32 bf16, 4-wave M-split, 16 batch cols per block.
//   wave mu owns h rows [16mu,16mu+16): full K=64 in 2 chained MFMAs
//   (16x16x32 ~5cyc issue vs 4x 8cyc for 32x32x16 in r8).
//   Pack: 2 cvt_pk_bf16 + 2 pk_max_i16, NO permlane -- C-regs go straight
//   to an LDS h-matrix stored in B-fragment chunk order.
//   Exchange: chunk(c,G) = h[8G..8G+8)[c] as u32x4; col stride padded to 9
//   chunks (read start-bank (c+g)%8 -> conflict-free b128; write b64 2-way).
//   Read-back IS the B operand: B_k = hbuf[c][4k + g].
// Layouts: C (m89-verified): col=lane&15, row=4*(lane>>4)+reg.
//   A (by symmetry w/ r1-verified 32x32): row=lane&15, k=8*(lane>>4)+e.
//   B: col=lane&15, k=8*(lane>>4)+e.
// Double-buffered hbuf + single {lgkmcnt(0); s_barrier} per step (WAR-safe:
// next write to buf q^1 while partner still reading q is a different buffer;
// reads of q are consumed (lgkm-waited) before that wave's next barrier).

typedef __bf16 bf16x8 __attribute__((ext_vector_type(8)));
typedef float f32x4 __attribute__((ext_vector_type(4)));
typedef unsigned int u32x4 __attribute__((ext_vector_type(4)));
typedef unsigned int u32x2 __attribute__((ext_vector_type(2)));

#define RNN_B 8192
#define RNN_T 512
#define RNN_H 64

__global__ __launch_bounds__(256, 1) void rnn_scan_kernel(
    const float* __restrict__ x,
    const float* __restrict__ Wxh,
    const float* __restrict__ Whh,
    const float* __restrict__ Why,
    float* __restrict__ out)
{
  const int tid  = threadIdx.x;
  const int mu   = tid >> 6;       // wave: owns h rows [16mu, 16mu+16)
  const int lane = tid & 63;
  const int c    = lane & 15;      // batch col within block
  const int g    = lane >> 4;      // lane group (C rows 4g..4g+3, B k 8g..8g+7)
  const int b0   = blockIdx.x * 16;

  // [buf][col][chunk G (pad 8->9)]; chunk = rows [8G,8G+8) of col c, bf16
  __shared__ u32x4 hbuf[2][16][9];           // 4608 B
  __shared__ float partial[4][16];

  // ---- A frags: W_hh[16mu + c][32k + 8g + e], k-halves k=0,1 ----
  bf16x8 A[2];
#pragma unroll
  for (int k = 0; k < 2; ++k) {
    const float* wp = Whh + (size_t)(16 * mu + c) * RNN_H + 32 * k + 8 * g;
    float4 w0 = *(const float4*)(wp);
    float4 w1 = *(const float4*)(wp + 4);
    bf16x8 f;
    f[0] = (__bf16)w0.x; f[1] = (__bf16)w0.y; f[2] = (__bf16)w0.z; f[3] = (__bf16)w0.w;
    f[4] = (__bf16)w1.x; f[5] = (__bf16)w1.y; f[6] = (__bf16)w1.z; f[7] = (__bf16)w1.w;
    A[k] = f;
  }

  // ---- w_x per C slot: row = 16mu + 4g + r ----
  f32x4 wxv;
#pragma unroll
  for (int r = 0; r < 4; ++r) wxv[r] = Wxh[16 * mu + 4 * g + r];

  const float* xrow = x + (size_t)(b0 + c) * RNN_T;
  float4 xc0 = *(const float4*)(xrow);
  float4 xc1 = *(const float4*)(xrow + 4);

  f32x4 acc = {};                  // own rows' pre-relu h (4 regs)
  u32x4 Bv0 = {}, Bv1 = {};        // B frags, k-halves (h_0 = 0)
  unsigned zero_u = 0;

  for (int tb = 0; tb < RNN_T; tb += 8) {
    const int tn = (tb + 8 < RNN_T) ? tb + 8 : tb;
    float4 xn0 = *(const float4*)(xrow + tn);
    float4 xn1 = *(const float4*)(xrow + tn + 4);
    const float xs[8] = {xc0.x, xc0.y, xc0.z, xc0.w, xc1.x, xc1.y, xc1.z, xc1.w};
#pragma unroll
    for (int j = 0; j < 8; ++j) {
      const float xv = xs[j];
      // h update: 2 chained 16x16x32 MFMAs, C-in = f32-exact x-term
      f32x4 a = wxv * xv;
      a = __builtin_amdgcn_mfma_f32_16x16x32_bf16(A[0], __builtin_bit_cast(bf16x8, Bv0), a, 0, 0, 0);
      a = __builtin_amdgcn_mfma_f32_16x16x32_bf16(A[1], __builtin_bit_cast(bf16x8, Bv1), a, 0, 0, 0);
      acc = a;

      // pack own 4 rows (16mu+4g+0..3, col c): cvt_pk (RNE) + relu on packed
      unsigned w0, w1;
      asm("v_cvt_pk_bf16_f32 %0, %1, %2" : "=v"(w0) : "v"(a[0]), "v"(a[1]));
      asm("v_cvt_pk_bf16_f32 %0, %1, %2" : "=v"(w1) : "v"(a[2]), "v"(a[3]));
      asm("v_pk_max_i16 %0, %1, %2" : "=v"(w0) : "v"(w0), "v"(zero_u));
      asm("v_pk_max_i16 %0, %1, %2" : "=v"(w1) : "v"(w1), "v"(zero_u));

      // write into chunk G = 2mu + (g>>1), half (g&1)  [rows 16mu+4g..+3]
      const int q = (j + 1) & 1;               // parity of t+1 (tb even)
      u32x2 wpair = {w0, w1};
      *(u32x2*)((char*)&hbuf[q][c][2 * mu + (g >> 1)] + 8 * (g & 1)) = wpair;
      asm volatile("s_waitcnt lgkmcnt(0)\n\ts_barrier" ::: "memory");
      // read B frags for next step: k-half k chunk G = 4k + g
      Bv0 = hbuf[q][c][g];
      Bv1 = hbuf[q][c][4 + g];
    }
    xc0 = xn0; xc1 = xn1;
  }

  // ---- epilogue: out[b] = sum_rows Why * relu(h_T) ----
  float pw = 0.0f;
#pragma unroll
  for (int r = 0; r < 4; ++r)
    pw += Why[16 * mu + 4 * g + r] * fmaxf(acc[r], 0.0f);
  pw += __shfl_xor(pw, 16, 64);
  pw += __shfl_xor(pw, 32, 64);
  if (lane < 16) partial[mu][c] = pw;
  __syncthreads();
  if (mu == 0 && lane < 16)
    out[b0 + c] = partial[0][c] + partial[1][c] + partial[2][c] + partial[3][c];
}

extern "C" void kernel_launch(void* const* d_in, const int* in_sizes, int n_in,
                              void* d_out, int out_size, void* d_ws, size_t ws_size,
                              hipStream_t stream) {
  const float* x   = (const float*)d_in[0];
  const float* Wxh = (const float*)d_in[1];
  const float* Whh = (const float*)d_in[2];
  const float* Why = (const float*)d_in[3];
  float* out = (float*)d_out;
  (void)in_sizes; (void)n_in; (void)out_size; (void)d_ws; (void)ws_size;
  rnn_scan_kernel<<<dim3(RNN_B / 16), dim3(256), 0, stream>>>(x, Wxh, Whh, Why, out);
}